// Round 1
// 247.936 us; speedup vs baseline: 1.1120x; 1.1120x over previous
//
#include <hip/hip_runtime.h>
#include <math.h>

// Problem constants (match reference)
#define B_ 4
#define L_ 2048
#define H_ 16
#define D_ 64
#define M_ 128
#define TC_ 64              // chunk length
#define NC_ (L_ / TC_)      // 32 chunks
#define EPSK 1e-6f
#define DATA_SCALE 0.35355339059327379f  // 64^{-1/4}
#define RATIO 0.08838834764831845f       // 128^{-1/2}

typedef __bf16 bf16;
typedef bf16 bf16x4 __attribute__((ext_vector_type(4)));
typedef bf16 bf16x8 __attribute__((ext_vector_type(8)));
typedef float floatx4 __attribute__((ext_vector_type(4)));

// padded row strides (bf16 elems): +8 keeps 16B alignment and shifts each row
// by 4 dwords -> a quarter-wave's 16 lr-lanes cover all 8 bank classes 2x (free)
#define PK128 136
#define PK64 72

__device__ __forceinline__ unsigned pk(bf16 a, bf16 b) {
    return (unsigned)__builtin_bit_cast(unsigned short, a) |
           ((unsigned)__builtin_bit_cast(unsigned short, b) << 16);
}
__device__ __forceinline__ void split2(float x, bf16& hi, bf16& lo) {
    hi = (bf16)x;
    lo = (bf16)(x - (float)hi);
}

// ---- order-preserving float<->uint for atomic max ----
__device__ __forceinline__ unsigned enc_f(float f) {
    unsigned u = __float_as_uint(f);
    return (u & 0x80000000u) ? ~u : (u | 0x80000000u);
}
__device__ __forceinline__ float dec_f(unsigned u) {
    unsigned b = (u & 0x80000000u) ? (u ^ 0x80000000u) : ~u;
    return __uint_as_float(b);
}

// ---------------------------------------------------------------------------
// One-time: split proj into hi/lo bf16 in MFMA B-fragment order.
// pf[(tc*2 + k0h)*64 + lane][e] = proj[16*tc + (lane&15)][k0h*32 + (lane>>4)*8 + e]
// 16 KB each (hi, lo) -> L1/L2-resident for all feat blocks. Also zeroes mx.
// ---------------------------------------------------------------------------
__global__ __launch_bounds__(256) void proj_split(const float* __restrict__ proj,
                                                  bf16* __restrict__ pfh,
                                                  bf16* __restrict__ pfl,
                                                  unsigned* __restrict__ mx) {
    int f = blockIdx.x * 256 + threadIdx.x;   // 0..1023 fragments
    if (blockIdx.x == 0 && threadIdx.x < B_ * H_) mx[threadIdx.x] = 0u;
    int tc = f >> 7, k0h = (f >> 6) & 1, lane = f & 63;
    int lr = lane & 15, quad = lane >> 4;
    const float* src = proj + (16 * tc + lr) * 64 + k0h * 32 + quad * 8;
    float4 x0 = *(const float4*)src;
    float4 x1 = *(const float4*)(src + 4);
    float a[8] = {x0.x, x0.y, x0.z, x0.w, x1.x, x1.y, x1.z, x1.w};
    bf16x8 hi, lo;
#pragma unroll
    for (int e = 0; e < 8; e++) {
        bf16 h = (bf16)a[e];
        hi[e] = h;
        lo[e] = (bf16)(a[e] - (float)h);
    }
    *(bf16x8*)(pfh + (size_t)f * 8) = hi;
    *(bf16x8*)(pfl + (size_t)f * 8) = lo;
}

// ---------------------------------------------------------------------------
// Feature map via MFMA with bf16 hi/lo split (fp32-accurate dd).
// Block = (b,h,c): 64 l-rows at fixed (b,h). A-frags: direct per-lane global
// loads + in-register split. B-frags: pre-split fragment-order global
// (L1-resident). Only LDS = sc (store repack) -> ~5 blocks/CU.
// MODE 0: k max pass (hi*hi only; max shift cancels in final ratio up to eps)
// MODE 1: k exp pass -> kp + kpT. MODE 2: q pass -> qp (per-row max).
// ---------------------------------------------------------------------------
template <int MODE>
__global__ __launch_bounds__(256) void feat_mfma(const float* __restrict__ data,
                                                 const bf16* __restrict__ pfh,
                                                 const bf16* __restrict__ pfl,
                                                 unsigned* __restrict__ mxk,
                                                 bf16* __restrict__ outp,
                                                 bf16* __restrict__ outT) {
    __shared__ __align__(16) bf16 sc[64 * 130];
    __shared__ float wred[4];

    int tid = threadIdx.x;
    int blk = blockIdx.x;
    int c = blk & 31, h = (blk >> 5) & 15, b = blk >> 9;
    int l0 = c * 64;
    int w = tid >> 6, lane = tid & 63, lr = lane & 15, quad = lane >> 4;

    // A-fragments: row 16w+lr, cols quad*8 (+0 / +32), scaled + hi/lo split
    const float* drow = data +
        ((size_t)(b * L_ + l0 + 16 * w + lr) * H_ + h) * D_ + quad * 8;
    bf16x8 ah[2], al[2];
    float ss = 0.f;
#pragma unroll
    for (int k0 = 0; k0 < 2; k0++) {
        float4 x0 = *(const float4*)(drow + k0 * 32);
        float4 x1 = *(const float4*)(drow + k0 * 32 + 4);
        float a[8] = {x0.x, x0.y, x0.z, x0.w, x1.x, x1.y, x1.z, x1.w};
#pragma unroll
        for (int e = 0; e < 8; e++) {
            float s = DATA_SCALE * a[e];
            if (MODE != 0) ss += s * s;
            bf16 hh = (bf16)s;
            ah[k0][e] = hh;
            if (MODE != 0) al[k0][e] = (bf16)(s - (float)hh);
        }
    }
    float ssrow = 0.f;
    if (MODE != 0) {
        // sum across quads (lanes lr, lr+16, lr+32, lr+48 hold row 16w+lr)
        ss += __shfl_xor(ss, 16, 64);
        ss += __shfl_xor(ss, 32, 64);
        ssrow = 0.5f * ss;
    }

    floatx4 acc[8];
#pragma unroll
    for (int tc = 0; tc < 8; tc++) acc[tc] = (floatx4){0.f, 0.f, 0.f, 0.f};

    const bf16x8* ph = (const bf16x8*)pfh + lane;
    const bf16x8* pl = (const bf16x8*)pfl + lane;
#pragma unroll
    for (int tc = 0; tc < 8; tc++) {
#pragma unroll
        for (int k0 = 0; k0 < 2; k0++) {
            bf16x8 bh = ph[(tc * 2 + k0) * 64];
            acc[tc] = __builtin_amdgcn_mfma_f32_16x16x32_bf16(ah[k0], bh, acc[tc], 0, 0, 0);
            if (MODE != 0) {
                bf16x8 bl = pl[(tc * 2 + k0) * 64];
                acc[tc] = __builtin_amdgcn_mfma_f32_16x16x32_bf16(al[k0], bh, acc[tc], 0, 0, 0);
                acc[tc] = __builtin_amdgcn_mfma_f32_16x16x32_bf16(ah[k0], bl, acc[tc], 0, 0, 0);
            }
        }
    }

    if (MODE == 0) {
        float mm = acc[0][0];
#pragma unroll
        for (int tc = 0; tc < 8; tc++)
#pragma unroll
            for (int reg = 0; reg < 4; reg++) mm = fmaxf(mm, acc[tc][reg]);
#pragma unroll
        for (int off = 1; off < 64; off <<= 1) mm = fmaxf(mm, __shfl_xor(mm, off, 64));
        if (lane == 0) wred[w] = mm;
        __syncthreads();
        if (tid == 0) {
            float g = fmaxf(fmaxf(wred[0], wred[1]), fmaxf(wred[2], wred[3]));
            atomicMax(&mxk[b * H_ + h], enc_f(g));
        }
        return;
    }

    int t0 = 16 * w + 4 * quad;
    float mxg = 0.f;
    if (MODE == 1) mxg = dec_f(mxk[b * H_ + h]);

    float rm[4];
    if (MODE == 2) {
#pragma unroll
        for (int reg = 0; reg < 4; reg++) {
            float m = acc[0][reg];
#pragma unroll
            for (int tc = 1; tc < 8; tc++) m = fmaxf(m, acc[tc][reg]);
            m = fmaxf(m, __shfl_xor(m, 1, 64));
            m = fmaxf(m, __shfl_xor(m, 2, 64));
            m = fmaxf(m, __shfl_xor(m, 4, 64));
            m = fmaxf(m, __shfl_xor(m, 8, 64));
            rm[reg] = m;
        }
    }

#pragma unroll
    for (int reg = 0; reg < 4; reg++) {
        // diag of output row t0+reg lives at lane lr' = 4*quad+reg (quad'=0)
        float dg = __shfl(ssrow, 4 * quad + reg, 64);
        float sh = (MODE == 1) ? (dg + mxg) : (dg + rm[reg]);
#pragma unroll
        for (int tc = 0; tc < 8; tc++) {
            float val = RATIO * (__expf(acc[tc][reg] - sh) + EPSK);
            sc[(t0 + reg) * 130 + 16 * tc + lr] = (bf16)val;
        }
    }
    __syncthreads();

#pragma unroll
    for (int i = 0; i < 16; i++) {
        int e = tid + 256 * i;           // 4096 uints
        int row = e >> 6, mp = e & 63;
        unsigned u = pk(sc[row * 130 + 2 * mp], sc[row * 130 + 2 * mp + 1]);
        *(unsigned*)(outp + ((size_t)(b * L_ + l0 + row) * H_ + h) * M_ + 2 * mp) = u;
    }
    if (MODE == 1) {
#pragma unroll
        for (int i = 0; i < 16; i++) {
            int e = tid + 256 * i;       // 4096 uints
            int m = e >> 5, t2 = (e & 31) * 2;
            unsigned u = pk(sc[t2 * 130 + m], sc[(t2 + 1) * 130 + m]);
            *(unsigned*)(outT + ((size_t)(b * H_ + h) * M_ + m) * L_ + l0 + t2) = u;
        }
    }
}

// ---------------------------------------------------------------------------
// V transpose: block = (b,h,c). v fp32 [b][l][h][d] -> vbT bf16 [b][h][d][l].
// ---------------------------------------------------------------------------
__global__ __launch_bounds__(256) void v_tr(const float* __restrict__ v,
                                            bf16* __restrict__ vbT) {
    __shared__ __align__(16) bf16 vt[64 * 66];
    int tid = threadIdx.x;
    int blk = blockIdx.x;
    int c = blk & 31, hh = (blk >> 5) & 15, b = blk >> 9;
#pragma unroll
    for (int i = 0; i < 4; i++) {
        int ch = tid + 256 * i;          // 1024 float4 chunks (64 rows x 16)
        int row = ch >> 4, c4 = ch & 15;
        size_t gb = ((size_t)(b * L_ + c * 64 + row) * H_ + hh) * D_;
        float4 x = *(const float4*)(v + gb + c4 * 4);
        unsigned* lp = (unsigned*)(vt + row * 66 + c4 * 4);
        lp[0] = pk((bf16)x.x, (bf16)x.y);
        lp[1] = pk((bf16)x.z, (bf16)x.w);
    }
    __syncthreads();
    size_t ob = (size_t)((b * H_ + hh) * D_) * (size_t)L_ + c * 64;
#pragma unroll
    for (int i = 0; i < 8; i++) {
        int e2 = tid + 256 * i;          // 2048 pairs
        int d = e2 >> 5, tau2 = (e2 & 31) * 2;
        *(unsigned*)(vbT + ob + (size_t)d * L_ + tau2) =
            pk(vt[tau2 * 66 + d], vt[(tau2 + 1) * 66 + d]);
    }
}

// ---------------------------------------------------------------------------
// Chunk sums via MFMA: S^T[d][m] = sum_tau v[tau][d]*kp[tau][m] (bf16 out,
// coalesced via LDS repack), ds[m] = sum_tau kp[tau][m] (fp32).
// ---------------------------------------------------------------------------
__global__ __launch_bounds__(256) void chunk_mfma(const bf16* __restrict__ kpT,
                                                  const bf16* __restrict__ vbT,
                                                  bf16* __restrict__ S,
                                                  float* __restrict__ ds) {
    __shared__ __align__(16) bf16 kT[128 * PK64];   // [m][tau] padded
    __shared__ __align__(16) bf16 vT[64 * PK64];    // [d][tau] padded
    int tid = threadIdx.x;
    int blk = blockIdx.x;
    int c = blk & 31, bh = blk >> 5;
    int l0 = c * 64;
#pragma unroll
    for (int i = 0; i < 4; i++) {
        int ch = tid + 256 * i;          // 1024 chunks (128 rows x 8)
        int m = ch >> 3, c8 = ch & 7;
        *(uint4*)(kT + m * PK64 + c8 * 8) =
            ((const uint4*)kpT)[(((size_t)bh * M_ + m) * L_ + l0) / 8 + c8];
    }
#pragma unroll
    for (int i = 0; i < 2; i++) {
        int ch = tid + 256 * i;          // 512 chunks (64 rows x 8)
        int d = ch >> 3, c8 = ch & 7;
        *(uint4*)(vT + d * PK64 + c8 * 8) =
            ((const uint4*)vbT)[(((size_t)bh * D_ + d) * L_ + l0) / 8 + c8];
    }
    __syncthreads();

    int w = tid >> 6, lane = tid & 63, lr = lane & 15, quad = lane >> 4;
    floatx4 acc[8];
#pragma unroll
    for (int tc = 0; tc < 8; tc++) acc[tc] = (floatx4){0.f, 0.f, 0.f, 0.f};
#pragma unroll
    for (int k0 = 0; k0 < 64; k0 += 32) {
        bf16x8 a = *(const bf16x8*)(vT + (16 * w + lr) * PK64 + k0 + quad * 8);
#pragma unroll
        for (int tc = 0; tc < 8; tc++) {
            bf16x8 bb = *(const bf16x8*)(kT + (16 * tc + lr) * PK64 + k0 + quad * 8);
            acc[tc] = __builtin_amdgcn_mfma_f32_16x16x32_bf16(a, bb, acc[tc], 0, 0, 0);
        }
    }

    // ds[m]: 2 threads per m, 32 taus each (reads kT before repack overwrites)
    float dsv = 0.f;
    {
        int m = tid >> 1, half = tid & 1;
        const bf16x8* kr = (const bf16x8*)(kT + m * PK64 + half * 32);
#pragma unroll
        for (int j = 0; j < 4; j++) {
            bf16x8 vv = kr[j];
#pragma unroll
            for (int e = 0; e < 8; e++) dsv += (float)vv[e];
        }
        dsv += __shfl_xor(dsv, 1, 64);
    }
    __syncthreads();

    // repack acc into kT area as flat [d][m] (64x128), then coalesced store
    bf16* scr = kT;
    int d0 = 16 * w + 4 * quad;
#pragma unroll
    for (int tc = 0; tc < 8; tc++)
#pragma unroll
        for (int reg = 0; reg < 4; reg++)
            scr[(d0 + reg) * 128 + 16 * tc + lr] = (bf16)acc[tc][reg];
    if ((tid & 1) == 0) ds[(size_t)blk * M_ + (tid >> 1)] = dsv;
    __syncthreads();
#pragma unroll
    for (int i = 0; i < 4; i++) {
        int e = tid + 256 * i;           // 1024 uint4
        ((uint4*)S)[(size_t)blk * 1024 + e] = ((const uint4*)scr)[e];
    }
}

// Exclusive prefix over chunks, bf16 in place (fp32 carries), 2 elems/thread.
__global__ void prefix_S(unsigned* __restrict__ S) {
    int blk = blockIdx.x;
    int seg = blk & 15, bh = blk >> 4;
    int p = seg * 256 + threadIdx.x;            // 0..4095 uint pairs per chunk
    size_t base = (size_t)bh * NC_ * 4096 + p;
    float c0 = 0.f, c1 = 0.f;
    for (int c = 0; c < NC_; c++) {
        size_t a = base + (size_t)c * 4096;
        unsigned u = S[a];
        float f0 = (float)__builtin_bit_cast(bf16, (unsigned short)(u & 0xffffu));
        float f1 = (float)__builtin_bit_cast(bf16, (unsigned short)(u >> 16));
        S[a] = pk((bf16)c0, (bf16)c1);
        c0 += f0; c1 += f1;
    }
}

__global__ void prefix_D(float* __restrict__ ds) {
    int bh = blockIdx.x;
    int m = threadIdx.x;
    size_t base = (size_t)bh * NC_ * M_ + m;
    float carry = 0.f;
    for (int c = 0; c < NC_; c++) {
        size_t a = base + (size_t)c * M_;
        float val = ds[a];
        ds[a] = carry;
        carry += val;
    }
}

// ---------------------------------------------------------------------------
// Main attention via MFMA. Block = (bh,c), 4 waves; wave w owns t-rows
// 16w..16w+15. Q A-frags live in registers (loaded from global, reused in
// phase1 & 2a). LDS arena: ks(64x136) | spT(64x136, sc aliases) | vT(64x72)
// = 44 KB -> 3 blocks/CU.
// ---------------------------------------------------------------------------
__global__ __launch_bounds__(256) void attn_mfma(const bf16* __restrict__ qp,
                                                 const bf16* __restrict__ kp,
                                                 const bf16* __restrict__ vbT,
                                                 const bf16* __restrict__ Sp,
                                                 const float* __restrict__ dp,
                                                 float* __restrict__ out) {
    __shared__ __align__(16) bf16 arena[64 * PK128 * 2 + 64 * PK64];
    bf16* ks  = arena;                    // 64 x 136
    bf16* spT = arena + 64 * PK128;       // 64 x 136 (S_prev^T [d][m])
    bf16* sc  = spT;                      // 64 x 72, aliases spT after phase1
    bf16* vT  = arena + 2 * 64 * PK128;   // 64 x 72   [d][tau]
    __shared__ float dprevL[128];
    __shared__ float den0_l[64];
    __shared__ float densc_l[64];

    int tid = threadIdx.x;
    int blk = blockIdx.x;
    int c = blk & 31, bh = blk >> 5;
    int h = bh & 15, b = bh >> 4;
    int l0 = c * 64;

    // stage ks (padded)
#pragma unroll
    for (int i = 0; i < 4; i++) {
        int ch = tid + 256 * i;          // 1024 chunks (64 rows x 16)
        int row = ch >> 4, c8 = ch & 15;
        size_t gb = (((size_t)(b * L_ + l0 + row) * H_ + h) * M_) / 8;
        *(uint4*)(ks + row * PK128 + c8 * 8) = ((const uint4*)kp)[gb + c8];
    }
    // stage spT (padded; global is contiguous [blk][d][m])
#pragma unroll
    for (int i = 0; i < 4; i++) {
        int ch = tid + 256 * i;
        int row = ch >> 4, c8 = ch & 15;
        *(uint4*)(spT + row * PK128 + c8 * 8) = ((const uint4*)Sp)[(size_t)blk * 1024 + ch];
    }
    // stage vT (padded)
#pragma unroll
    for (int i = 0; i < 2; i++) {
        int ch = tid + 256 * i;          // 512 chunks
        int d = ch >> 3, c8 = ch & 7;
        *(uint4*)(vT + d * PK64 + c8 * 8) =
            ((const uint4*)vbT)[(((size_t)bh * D_ + d) * L_ + l0) / 8 + c8];
    }
    if (tid < 128) dprevL[tid] = dp[(size_t)blk * M_ + tid];
    __syncthreads();

    // den0[t] = qp_t . dprev  (qp straight from global, vectorized)
    {
        int t = tid >> 2, p = tid & 3;
        const bf16* qrow = qp + ((size_t)(b * L_ + l0 + t) * H_ + h) * M_ + p * 32;
        float s = 0.f;
#pragma unroll
        for (int j = 0; j < 4; j++) {
            bf16x8 vv = *(const bf16x8*)(qrow + 8 * j);
#pragma unroll
            for (int e = 0; e < 8; e++) s += (float)vv[e] * dprevL[p * 32 + 8 * j + e];
        }
        s += __shfl_xor(s, 1, 64);
        s += __shfl_xor(s, 2, 64);
        if (p == 0) den0_l[t] = s;
    }

    int w = tid >> 6, lane = tid & 63, lr = lane & 15, quad = lane >> 4;

    // Q A-frags in registers, reused by phase1 + phase2a
    bf16x8 af[4];
    {
        const bf16* qb = qp + ((size_t)(b * L_ + l0 + 16 * w + lr) * H_ + h) * M_ + quad * 8;
#pragma unroll
        for (int k = 0; k < 4; k++) af[k] = *(const bf16x8*)(qb + 32 * k);
    }

    floatx4 acc[4];
#pragma unroll
    for (int tc = 0; tc < 4; tc++) acc[tc] = (floatx4){0.f, 0.f, 0.f, 0.f};

    // phase 1: Qp . S_prev (B rows = spT, padded stride)
#pragma unroll
    for (int ki = 0; ki < 4; ki++) {
#pragma unroll
        for (int tc = 0; tc < 4; tc++) {
            bf16x8 bb = *(const bf16x8*)(spT + (16 * tc + lr) * PK128 + 32 * ki + quad * 8);
            acc[tc] = __builtin_amdgcn_mfma_f32_16x16x32_bf16(af[ki], bb, acc[tc], 0, 0, 0);
        }
    }

    // phase 2a: scores (tiles tc<=w)
    floatx4 acc2[4];
#pragma unroll
    for (int tc = 0; tc < 4; tc++) acc2[tc] = (floatx4){0.f, 0.f, 0.f, 0.f};
#pragma unroll
    for (int ki = 0; ki < 4; ki++) {
        for (int tc = 0; tc <= w; tc++) {
            bf16x8 bb = *(const bf16x8*)(ks + (16 * tc + lr) * PK128 + 32 * ki + quad * 8);
            acc2[tc] = __builtin_amdgcn_mfma_f32_16x16x32_bf16(af[ki], bb, acc2[tc], 0, 0, 0);
        }
    }
    __syncthreads();   // all phase-1 spT reads done before sc (alias) is written

    // mask + den partials + bf16 scores to LDS (full 64 cols incl. zeros)
    {
        float dsum[4] = {0.f, 0.f, 0.f, 0.f};
        int t0 = 16 * w + 4 * quad;
#pragma unroll
        for (int tc = 0; tc < 4; tc++) {
#pragma unroll
            for (int reg = 0; reg < 4; reg++) {
                int tg = t0 + reg, tau = 16 * tc + lr;
                float vv = (tc <= w) ? acc2[tc][reg] : 0.f;
                if (tau > tg) vv = 0.f;
                dsum[reg] += vv;
                sc[tg * PK64 + tau] = (bf16)vv;
            }
        }
#pragma unroll
        for (int reg = 0; reg < 4; reg++) {
            float s = dsum[reg];
            s += __shfl_xor(s, 1, 64);
            s += __shfl_xor(s, 2, 64);
            s += __shfl_xor(s, 4, 64);
            s += __shfl_xor(s, 8, 64);
            if (lr == 0) densc_l[t0 + reg] = s;
        }
    }
    __syncthreads();

    // phase 2b: Sc . V  (waves 0,1 only need tau<32)
    {
        int kmax = (w >= 2) ? 64 : 32;
        for (int k0 = 0; k0 < kmax; k0 += 32) {
            bf16x8 a = *(const bf16x8*)(sc + (16 * w + lr) * PK64 + k0 + quad * 8);
#pragma unroll
            for (int tc = 0; tc < 4; tc++) {
                bf16x8 bb = *(const bf16x8*)(vT + (16 * tc + lr) * PK64 + k0 + quad * 8);
                acc[tc] = __builtin_amdgcn_mfma_f32_16x16x32_bf16(a, bb, acc[tc], 0, 0, 0);
            }
        }
    }

    // epilogue
    {
        int t0 = 16 * w + 4 * quad;
        float inv[4];
#pragma unroll
        for (int reg = 0; reg < 4; reg++)
            inv[reg] = 1.0f / (den0_l[t0 + reg] + densc_l[t0 + reg]);
#pragma unroll
        for (int tc = 0; tc < 4; tc++)
#pragma unroll
            for (int reg = 0; reg < 4; reg++)
                out[((size_t)(b * L_ + l0 + t0 + reg) * H_ + h) * D_ + 16 * tc + lr] =
                    acc[tc][reg] * inv[reg];
    }
}

extern "C" void kernel_launch(void* const* d_in, const int* in_sizes, int n_in,
                              void* d_out, int out_size, void* d_ws, size_t ws_size,
                              hipStream_t stream) {
    const float* q = (const float*)d_in[0];
    const float* k = (const float*)d_in[1];
    const float* v = (const float*)d_in[2];
    const float* proj = (const float*)d_in[3];
    float* out = (float*)d_out;
    char* W = (char*)d_ws;

    // workspace layout (bytes)
    bf16* qp   = (bf16*)(W);                       //  33,554,432  [b][l][h][m]
    bf16* kp   = (bf16*)(W + 33554432ull);         //  33,554,432  [b][l][h][m]
    bf16* kpT  = (bf16*)(W + 67108864ull);         //  33,554,432  [b][h][m][l]
    bf16* vbT  = (bf16*)(W + 100663296ull);        //  16,777,216  [b][h][d][l]
    bf16* S    = (bf16*)(W + 117440512ull);        //  33,554,432  [bh,c][d][m]
    float* ds  = (float*)(W + 150994944ull);       //   1,048,576
    unsigned* mx = (unsigned*)(W + 152043520ull);  //   256
    bf16* pfh  = (bf16*)(W + 152043776ull);        //   16,384 proj hi frags
    bf16* pfl  = (bf16*)(W + 152060160ull);        //   16,384 proj lo frags

    hipLaunchKernelGGL(proj_split, dim3(4), dim3(256), 0, stream, proj, pfh, pfl, mx);
    hipLaunchKernelGGL((feat_mfma<0>), dim3(2048), dim3(256), 0, stream,
                       k, pfh, pfl, mx, (bf16*)nullptr, (bf16*)nullptr);
    hipLaunchKernelGGL((feat_mfma<1>), dim3(2048), dim3(256), 0, stream,
                       k, pfh, pfl, mx, kp, kpT);
    hipLaunchKernelGGL((feat_mfma<2>), dim3(2048), dim3(256), 0, stream,
                       q, pfh, pfl, mx, qp, (bf16*)nullptr);
    hipLaunchKernelGGL(v_tr, dim3(2048), dim3(256), 0, stream, v, vbT);
    hipLaunchKernelGGL(chunk_mfma, dim3(2048), dim3(256), 0, stream, kpT, vbT, S, ds);
    hipLaunchKernelGGL(prefix_S, dim3(1024), dim3(256), 0, stream, (unsigned*)S);
    hipLaunchKernelGGL(prefix_D, dim3(64), dim3(128), 0, stream, ds);
    hipLaunchKernelGGL(attn_mfma, dim3(2048), dim3(256), 0, stream,
                       qp, kp, vbT, S, ds, out);
}

// Round 2
// 235.074 us; speedup vs baseline: 1.1728x; 1.0547x over previous
//
#include <hip/hip_runtime.h>
#include <math.h>

// Problem constants (match reference)
#define B_ 4
#define L_ 2048
#define H_ 16
#define D_ 64
#define M_ 128
#define TC_ 64              // chunk length
#define NC_ (L_ / TC_)      // 32 chunks
#define EPSK 1e-6f
#define DATA_SCALE 0.35355339059327379f  // 64^{-1/4}
#define RATIO 0.08838834764831845f       // 128^{-1/2}

typedef __bf16 bf16;
typedef bf16 bf16x4 __attribute__((ext_vector_type(4)));
typedef bf16 bf16x8 __attribute__((ext_vector_type(8)));
typedef float floatx4 __attribute__((ext_vector_type(4)));

#define PK128 136
#define PK64 72

__device__ __forceinline__ unsigned pk(bf16 a, bf16 b) {
    return (unsigned)__builtin_bit_cast(unsigned short, a) |
           ((unsigned)__builtin_bit_cast(unsigned short, b) << 16);
}

// ---- order-preserving float<->uint for atomic max ----
__device__ __forceinline__ unsigned enc_f(float f) {
    unsigned u = __float_as_uint(f);
    return (u & 0x80000000u) ? ~u : (u | 0x80000000u);
}
__device__ __forceinline__ float dec_f(unsigned u) {
    unsigned b = (u & 0x80000000u) ? (u ^ 0x80000000u) : ~u;
    return __uint_as_float(b);
}

// ---------------------------------------------------------------------------
// One-time: split proj into hi/lo bf16 in MFMA B-fragment order.
// pf[(tc*2 + k0h)*64 + lane][e] = proj[16*tc + (lane&15)][k0h*32 + (lane>>4)*8 + e]
// 16 KB each (hi, lo) -> L1/L2-resident for all feat blocks. Also zeroes mx.
// ---------------------------------------------------------------------------
__global__ __launch_bounds__(256) void proj_split(const float* __restrict__ proj,
                                                  bf16* __restrict__ pfh,
                                                  bf16* __restrict__ pfl,
                                                  unsigned* __restrict__ mx) {
    int f = blockIdx.x * 256 + threadIdx.x;   // 0..1023 fragments
    if (blockIdx.x == 0 && threadIdx.x < B_ * H_) mx[threadIdx.x] = 0u;
    int tc = f >> 7, k0h = (f >> 6) & 1, lane = f & 63;
    int lr = lane & 15, quad = lane >> 4;
    const float* src = proj + (16 * tc + lr) * 64 + k0h * 32 + quad * 8;
    float4 x0 = *(const float4*)src;
    float4 x1 = *(const float4*)(src + 4);
    float a[8] = {x0.x, x0.y, x0.z, x0.w, x1.x, x1.y, x1.z, x1.w};
    bf16x8 hi, lo;
#pragma unroll
    for (int e = 0; e < 8; e++) {
        bf16 h = (bf16)a[e];
        hi[e] = h;
        lo[e] = (bf16)(a[e] - (float)h);
    }
    *(bf16x8*)(pfh + (size_t)f * 8) = hi;
    *(bf16x8*)(pfl + (size_t)f * 8) = lo;
}

// ---------------------------------------------------------------------------
// Feature-map body (device fn). A-frags per-lane from global + in-register
// hi/lo split; B-frags from pre-split fragment-order global (L1-resident).
// MODE 0: k max pass (hi*hi only). MODE 1: k exp -> kp + kpT. MODE 2: q -> qp.
// ---------------------------------------------------------------------------
template <int MODE>
__device__ __forceinline__ void feat_body(const float* __restrict__ data,
                                          const bf16* __restrict__ pfh,
                                          const bf16* __restrict__ pfl,
                                          unsigned* __restrict__ mxk,
                                          bf16* __restrict__ outp,
                                          bf16* __restrict__ outT,
                                          int blk, bf16* sc, float* wred) {
    int tid = threadIdx.x;
    int c = blk & 31, h = (blk >> 5) & 15, b = blk >> 9;
    int l0 = c * 64;
    int w = tid >> 6, lane = tid & 63, lr = lane & 15, quad = lane >> 4;

    const float* drow = data +
        ((size_t)(b * L_ + l0 + 16 * w + lr) * H_ + h) * D_ + quad * 8;
    bf16x8 ah[2], al[2];
    float ss = 0.f;
#pragma unroll
    for (int k0 = 0; k0 < 2; k0++) {
        float4 x0 = *(const float4*)(drow + k0 * 32);
        float4 x1 = *(const float4*)(drow + k0 * 32 + 4);
        float a[8] = {x0.x, x0.y, x0.z, x0.w, x1.x, x1.y, x1.z, x1.w};
#pragma unroll
        for (int e = 0; e < 8; e++) {
            float s = DATA_SCALE * a[e];
            if (MODE != 0) ss += s * s;
            bf16 hh = (bf16)s;
            ah[k0][e] = hh;
            if (MODE != 0) al[k0][e] = (bf16)(s - (float)hh);
        }
    }
    float ssrow = 0.f;
    if (MODE != 0) {
        ss += __shfl_xor(ss, 16, 64);
        ss += __shfl_xor(ss, 32, 64);
        ssrow = 0.5f * ss;
    }

    floatx4 acc[8];
#pragma unroll
    for (int tc = 0; tc < 8; tc++) acc[tc] = (floatx4){0.f, 0.f, 0.f, 0.f};

    const bf16x8* ph = (const bf16x8*)pfh + lane;
    const bf16x8* pl = (const bf16x8*)pfl + lane;
#pragma unroll
    for (int tc = 0; tc < 8; tc++) {
#pragma unroll
        for (int k0 = 0; k0 < 2; k0++) {
            bf16x8 bh = ph[(tc * 2 + k0) * 64];
            acc[tc] = __builtin_amdgcn_mfma_f32_16x16x32_bf16(ah[k0], bh, acc[tc], 0, 0, 0);
            if (MODE != 0) {
                bf16x8 bl = pl[(tc * 2 + k0) * 64];
                acc[tc] = __builtin_amdgcn_mfma_f32_16x16x32_bf16(al[k0], bh, acc[tc], 0, 0, 0);
                acc[tc] = __builtin_amdgcn_mfma_f32_16x16x32_bf16(ah[k0], bl, acc[tc], 0, 0, 0);
            }
        }
    }

    if (MODE == 0) {
        float mm = acc[0][0];
#pragma unroll
        for (int tc = 0; tc < 8; tc++)
#pragma unroll
            for (int reg = 0; reg < 4; reg++) mm = fmaxf(mm, acc[tc][reg]);
#pragma unroll
        for (int off = 1; off < 64; off <<= 1) mm = fmaxf(mm, __shfl_xor(mm, off, 64));
        if (lane == 0) wred[w] = mm;
        __syncthreads();
        if (tid == 0) {
            float g = fmaxf(fmaxf(wred[0], wred[1]), fmaxf(wred[2], wred[3]));
            atomicMax(&mxk[b * H_ + h], enc_f(g));
        }
        return;
    }

    int t0 = 16 * w + 4 * quad;
    float mxg = 0.f;
    if (MODE == 1) mxg = dec_f(mxk[b * H_ + h]);

    float rm[4];
    if (MODE == 2) {
#pragma unroll
        for (int reg = 0; reg < 4; reg++) {
            float m = acc[0][reg];
#pragma unroll
            for (int tc = 1; tc < 8; tc++) m = fmaxf(m, acc[tc][reg]);
            m = fmaxf(m, __shfl_xor(m, 1, 64));
            m = fmaxf(m, __shfl_xor(m, 2, 64));
            m = fmaxf(m, __shfl_xor(m, 4, 64));
            m = fmaxf(m, __shfl_xor(m, 8, 64));
            rm[reg] = m;
        }
    }

#pragma unroll
    for (int reg = 0; reg < 4; reg++) {
        float dg = __shfl(ssrow, 4 * quad + reg, 64);
        float sh = (MODE == 1) ? (dg + mxg) : (dg + rm[reg]);
#pragma unroll
        for (int tc = 0; tc < 8; tc++) {
            float val = RATIO * (__expf(acc[tc][reg] - sh) + EPSK);
            sc[(t0 + reg) * 130 + 16 * tc + lr] = (bf16)val;
        }
    }
    __syncthreads();

#pragma unroll
    for (int i = 0; i < 16; i++) {
        int e = tid + 256 * i;           // 4096 uints
        int row = e >> 6, mp = e & 63;
        unsigned u = pk(sc[row * 130 + 2 * mp], sc[row * 130 + 2 * mp + 1]);
        *(unsigned*)(outp + ((size_t)(b * L_ + l0 + row) * H_ + h) * M_ + 2 * mp) = u;
    }
    if (MODE == 1) {
#pragma unroll
        for (int i = 0; i < 16; i++) {
            int e = tid + 256 * i;       // 4096 uints
            int m = e >> 5, t2 = (e & 31) * 2;
            unsigned u = pk(sc[t2 * 130 + m], sc[(t2 + 1) * 130 + m]);
            *(unsigned*)(outT + ((size_t)(b * H_ + h) * M_ + m) * L_ + l0 + t2) = u;
        }
    }
}

// V transpose body: v fp32 [b][l][h][d] -> vbT bf16 [b][h][d][l].
__device__ __forceinline__ void vtr_body(const float* __restrict__ v,
                                         bf16* __restrict__ vbT,
                                         int blk, bf16* vt) {     // vt: 64*66
    int tid = threadIdx.x;
    int c = blk & 31, hh = (blk >> 5) & 15, b = blk >> 9;
#pragma unroll
    for (int i = 0; i < 4; i++) {
        int ch = tid + 256 * i;          // 1024 float4 chunks (64 rows x 16)
        int row = ch >> 4, c4 = ch & 15;
        size_t gb = ((size_t)(b * L_ + c * 64 + row) * H_ + hh) * D_;
        float4 x = *(const float4*)(v + gb + c4 * 4);
        unsigned* lp = (unsigned*)(vt + row * 66 + c4 * 4);
        lp[0] = pk((bf16)x.x, (bf16)x.y);
        lp[1] = pk((bf16)x.z, (bf16)x.w);
    }
    __syncthreads();
    size_t ob = (size_t)((b * H_ + hh) * D_) * (size_t)L_ + c * 64;
#pragma unroll
    for (int i = 0; i < 8; i++) {
        int e2 = tid + 256 * i;          // 2048 pairs
        int d = e2 >> 5, tau2 = (e2 & 31) * 2;
        *(unsigned*)(vbT + ob + (size_t)d * L_ + tau2) =
            pk(vt[tau2 * 66 + d], vt[(tau2 + 1) * 66 + d]);
    }
}

// Merged independent pre-passes: blk<2048 q-pass, <4096 k-max pass, else v_tr.
__global__ __launch_bounds__(256) void pre3(const float* __restrict__ q,
                                            const float* __restrict__ k,
                                            const float* __restrict__ v,
                                            const bf16* __restrict__ pfh,
                                            const bf16* __restrict__ pfl,
                                            unsigned* __restrict__ mxk,
                                            bf16* __restrict__ qp,
                                            bf16* __restrict__ vbT) {
    __shared__ __align__(16) bf16 arena[64 * 130];
    __shared__ float wred[4];
    int blk = blockIdx.x;
    if (blk < 2048) {
        feat_body<2>(q, pfh, pfl, mxk, qp, (bf16*)nullptr, blk, arena, wred);
    } else if (blk < 4096) {
        feat_body<0>(k, pfh, pfl, mxk, (bf16*)nullptr, (bf16*)nullptr, blk - 2048,
                     arena, wred);
    } else {
        vtr_body(v, vbT, blk - 4096, arena);
    }
}

// k exp pass (needs completed mxk)
__global__ __launch_bounds__(256) void feat_k(const float* __restrict__ k,
                                              const bf16* __restrict__ pfh,
                                              const bf16* __restrict__ pfl,
                                              unsigned* __restrict__ mxk,
                                              bf16* __restrict__ kp,
                                              bf16* __restrict__ kpT) {
    __shared__ __align__(16) bf16 arena[64 * 130];
    __shared__ float wred[4];
    feat_body<1>(k, pfh, pfl, mxk, kp, kpT, blockIdx.x, arena, wred);
}

// ---------------------------------------------------------------------------
// Chunk sums via MFMA: S^T[d][m] = sum_tau v[tau][d]*kp[tau][m] (bf16 out,
// coalesced via LDS repack), ds[m] = sum_tau kp[tau][m] (fp32).
// ---------------------------------------------------------------------------
__global__ __launch_bounds__(256) void chunk_mfma(const bf16* __restrict__ kpT,
                                                  const bf16* __restrict__ vbT,
                                                  bf16* __restrict__ S,
                                                  float* __restrict__ ds) {
    __shared__ __align__(16) bf16 kT[128 * PK64];   // [m][tau] padded
    __shared__ __align__(16) bf16 vT[64 * PK64];    // [d][tau] padded
    int tid = threadIdx.x;
    int blk = blockIdx.x;
    int c = blk & 31, bh = blk >> 5;
    int l0 = c * 64;
#pragma unroll
    for (int i = 0; i < 4; i++) {
        int ch = tid + 256 * i;          // 1024 chunks (128 rows x 8)
        int m = ch >> 3, c8 = ch & 7;
        *(uint4*)(kT + m * PK64 + c8 * 8) =
            ((const uint4*)kpT)[(((size_t)bh * M_ + m) * L_ + l0) / 8 + c8];
    }
#pragma unroll
    for (int i = 0; i < 2; i++) {
        int ch = tid + 256 * i;          // 512 chunks (64 rows x 8)
        int d = ch >> 3, c8 = ch & 7;
        *(uint4*)(vT + d * PK64 + c8 * 8) =
            ((const uint4*)vbT)[(((size_t)bh * D_ + d) * L_ + l0) / 8 + c8];
    }
    __syncthreads();

    int w = tid >> 6, lane = tid & 63, lr = lane & 15, quad = lane >> 4;
    floatx4 acc[8];
#pragma unroll
    for (int tc = 0; tc < 8; tc++) acc[tc] = (floatx4){0.f, 0.f, 0.f, 0.f};
#pragma unroll
    for (int k0 = 0; k0 < 64; k0 += 32) {
        bf16x8 a = *(const bf16x8*)(vT + (16 * w + lr) * PK64 + k0 + quad * 8);
#pragma unroll
        for (int tc = 0; tc < 8; tc++) {
            bf16x8 bb = *(const bf16x8*)(kT + (16 * tc + lr) * PK64 + k0 + quad * 8);
            acc[tc] = __builtin_amdgcn_mfma_f32_16x16x32_bf16(a, bb, acc[tc], 0, 0, 0);
        }
    }

    // ds[m]: 2 threads per m, 32 taus each (reads kT before repack overwrites)
    float dsv = 0.f;
    {
        int m = tid >> 1, half = tid & 1;
        const bf16x8* kr = (const bf16x8*)(kT + m * PK64 + half * 32);
#pragma unroll
        for (int j = 0; j < 4; j++) {
            bf16x8 vv = kr[j];
#pragma unroll
            for (int e = 0; e < 8; e++) dsv += (float)vv[e];
        }
        dsv += __shfl_xor(dsv, 1, 64);
    }
    __syncthreads();

    // repack acc into kT area as flat [d][m] (64x128), then coalesced store
    bf16* scr = kT;
    int d0 = 16 * w + 4 * quad;
#pragma unroll
    for (int tc = 0; tc < 8; tc++)
#pragma unroll
        for (int reg = 0; reg < 4; reg++)
            scr[(d0 + reg) * 128 + 16 * tc + lr] = (bf16)acc[tc][reg];
    if ((tid & 1) == 0) ds[(size_t)blk * M_ + (tid >> 1)] = dsv;
    __syncthreads();
#pragma unroll
    for (int i = 0; i < 4; i++) {
        int e = tid + 256 * i;           // 1024 uint4
        ((uint4*)S)[(size_t)blk * 1024 + e] = ((const uint4*)scr)[e];
    }
}

// Exclusive prefix over chunks, bf16 in place (fp32 carries). All 32 loads
// prefetched to registers (breaks the serial load->store latency chain).
// seg==0 blocks also do the ds prefix (fused old prefix_D).
__global__ void prefix_SD(unsigned* __restrict__ S, float* __restrict__ ds) {
    int blk = blockIdx.x;
    int seg = blk & 15, bh = blk >> 4;
    int p = seg * 256 + threadIdx.x;            // 0..4095 uint pairs per chunk
    size_t base = (size_t)bh * NC_ * 4096 + p;
    unsigned uv[NC_];
#pragma unroll
    for (int c = 0; c < NC_; c++) uv[c] = S[base + (size_t)c * 4096];
    float c0 = 0.f, c1 = 0.f;
#pragma unroll
    for (int c = 0; c < NC_; c++) {
        unsigned u = uv[c];
        float f0 = (float)__builtin_bit_cast(bf16, (unsigned short)(u & 0xffffu));
        float f1 = (float)__builtin_bit_cast(bf16, (unsigned short)(u >> 16));
        S[base + (size_t)c * 4096] = pk((bf16)c0, (bf16)c1);
        c0 += f0; c1 += f1;
    }
    if (seg == 0 && threadIdx.x < 128) {
        int m = threadIdx.x;
        size_t dbase = (size_t)bh * NC_ * M_ + m;
        float dv[NC_];
#pragma unroll
        for (int c = 0; c < NC_; c++) dv[c] = ds[dbase + (size_t)c * M_];
        float carry = 0.f;
#pragma unroll
        for (int c = 0; c < NC_; c++) {
            ds[dbase + (size_t)c * M_] = carry;
            carry += dv[c];
        }
    }
}

// ---------------------------------------------------------------------------
// Main attention via MFMA. Block = (bh,c), 4 waves; wave w owns t-rows
// 16w..16w+15. Q A-frags in registers. Sp/kp B-frags read DIRECTLY from
// global per-lane (each block's tiles are private -> LDS staging bought no
// reuse). sc is wave-local (each wave writes+reads only its own 16 rows) ->
// single barrier. LDS: vT(9.2K)+sc(9.2K)+dprev(0.5K) ~ 19 KB.
// ---------------------------------------------------------------------------
__global__ __launch_bounds__(256, 4) void attn_mfma(const bf16* __restrict__ qp,
                                                    const bf16* __restrict__ kp,
                                                    const bf16* __restrict__ vbT,
                                                    const bf16* __restrict__ Sp,
                                                    const float* __restrict__ dp,
                                                    float* __restrict__ out) {
    __shared__ __align__(16) bf16 vT[64 * PK64];   // [d][tau]
    __shared__ __align__(16) bf16 sc[64 * PK64];   // [t][tau], wave-local rows
    __shared__ float dprevL[128];

    int tid = threadIdx.x;
    int blk = blockIdx.x;
    int c = blk & 31, bh = blk >> 5;
    int h = bh & 15, b = bh >> 4;
    int l0 = c * 64;
    int w = tid >> 6, lane = tid & 63, lr = lane & 15, quad = lane >> 4;

    // stage vT (padded)
#pragma unroll
    for (int i = 0; i < 2; i++) {
        int ch = tid + 256 * i;          // 512 chunks
        int d = ch >> 3, c8 = ch & 7;
        *(uint4*)(vT + d * PK64 + c8 * 8) =
            ((const uint4*)vbT)[(((size_t)bh * D_ + d) * L_ + l0) / 8 + c8];
    }
    if (tid < 128) dprevL[tid] = dp[(size_t)blk * M_ + tid];

    // Q A-frags in registers (reused by phase1 + phase2a + den0)
    bf16x8 af[4];
    {
        const bf16* qb = qp + ((size_t)(b * L_ + l0 + 16 * w + lr) * H_ + h) * M_ + quad * 8;
#pragma unroll
        for (int k = 0; k < 4; k++) af[k] = *(const bf16x8*)(qb + 32 * k);
    }
    __syncthreads();

    // den0[16w+lr] = qp_row . dprev, from af frags (quad holds 8*4 of 128 m)
    float den0v = 0.f;
#pragma unroll
    for (int k = 0; k < 4; k++)
#pragma unroll
        for (int e = 0; e < 8; e++)
            den0v += (float)af[k][e] * dprevL[quad * 8 + 32 * k + e];
    den0v += __shfl_xor(den0v, 16, 64);
    den0v += __shfl_xor(den0v, 32, 64);

    floatx4 acc[4];
#pragma unroll
    for (int tc = 0; tc < 4; tc++) acc[tc] = (floatx4){0.f, 0.f, 0.f, 0.f};

    // phase 1: Qp . S_prev, B-frags direct from global (block-private tile)
    {
        const bf16* spb = Sp + (size_t)blk * 8192;
#pragma unroll
        for (int ki = 0; ki < 4; ki++) {
#pragma unroll
            for (int tc = 0; tc < 4; tc++) {
                bf16x8 bb = *(const bf16x8*)(spb + (16 * tc + lr) * 128 + 32 * ki + quad * 8);
                acc[tc] = __builtin_amdgcn_mfma_f32_16x16x32_bf16(af[ki], bb, acc[tc], 0, 0, 0);
            }
        }
    }

    // phase 2a: scores (tiles tc<=w), B-frags direct from global kp
    floatx4 acc2[4];
#pragma unroll
    for (int tc = 0; tc < 4; tc++) acc2[tc] = (floatx4){0.f, 0.f, 0.f, 0.f};
    {
        const bf16* kpb = kp + ((size_t)(b * L_ + l0) * H_ + h) * M_ + quad * 8;
#pragma unroll
        for (int ki = 0; ki < 4; ki++) {
            for (int tc = 0; tc <= w; tc++) {
                bf16x8 bb = *(const bf16x8*)(kpb + (size_t)(16 * tc + lr) * (H_ * M_) + 32 * ki);
                acc2[tc] = __builtin_amdgcn_mfma_f32_16x16x32_bf16(af[ki], bb, acc2[tc], 0, 0, 0);
            }
        }
    }

    // mask + den partials + bf16 scores to LDS (wave-local rows, no barrier)
    int t0 = 16 * w + 4 * quad;
    float densc[4];
    {
        float dsum[4] = {0.f, 0.f, 0.f, 0.f};
#pragma unroll
        for (int tc = 0; tc < 4; tc++) {
#pragma unroll
            for (int reg = 0; reg < 4; reg++) {
                int tg = t0 + reg, tau = 16 * tc + lr;
                float vv = (tc <= w) ? acc2[tc][reg] : 0.f;
                if (tau > tg) vv = 0.f;
                dsum[reg] += vv;
                sc[tg * PK64 + tau] = (bf16)vv;
            }
        }
#pragma unroll
        for (int reg = 0; reg < 4; reg++) {
            float s = dsum[reg];
            s += __shfl_xor(s, 1, 64);
            s += __shfl_xor(s, 2, 64);
            s += __shfl_xor(s, 4, 64);
            s += __shfl_xor(s, 8, 64);
            densc[reg] = s;              // row t0+reg, valid on all lr lanes
        }
    }

    // phase 2b: Sc . V (sc rows 16w.. are this wave's own; vT ready since barrier)
    {
        int kmax = (w >= 2) ? 64 : 32;
        for (int k0 = 0; k0 < kmax; k0 += 32) {
            bf16x8 a = *(const bf16x8*)(sc + (16 * w + lr) * PK64 + k0 + quad * 8);
#pragma unroll
            for (int tc = 0; tc < 4; tc++) {
                bf16x8 bb = *(const bf16x8*)(vT + (16 * tc + lr) * PK64 + k0 + quad * 8);
                acc[tc] = __builtin_amdgcn_mfma_f32_16x16x32_bf16(a, bb, acc[tc], 0, 0, 0);
            }
        }
    }

    // epilogue
    {
        float inv[4];
#pragma unroll
        for (int reg = 0; reg < 4; reg++) {
            float d0 = __shfl(den0v, 4 * quad + reg, 64);  // row 16w+4q+reg
            inv[reg] = 1.0f / (d0 + densc[reg]);
        }
#pragma unroll
        for (int tc = 0; tc < 4; tc++)
#pragma unroll
            for (int reg = 0; reg < 4; reg++)
                out[((size_t)(b * L_ + l0 + t0 + reg) * H_ + h) * D_ + 16 * tc + lr] =
                    acc[tc][reg] * inv[reg];
    }
}

extern "C" void kernel_launch(void* const* d_in, const int* in_sizes, int n_in,
                              void* d_out, int out_size, void* d_ws, size_t ws_size,
                              hipStream_t stream) {
    const float* q = (const float*)d_in[0];
    const float* k = (const float*)d_in[1];
    const float* v = (const float*)d_in[2];
    const float* proj = (const float*)d_in[3];
    float* out = (float*)d_out;
    char* W = (char*)d_ws;

    // workspace layout (bytes)
    bf16* qp   = (bf16*)(W);                       //  33,554,432  [b][l][h][m]
    bf16* kp   = (bf16*)(W + 33554432ull);         //  33,554,432  [b][l][h][m]
    bf16* kpT  = (bf16*)(W + 67108864ull);         //  33,554,432  [b][h][m][l]
    bf16* vbT  = (bf16*)(W + 100663296ull);        //  16,777,216  [b][h][d][l]
    bf16* S    = (bf16*)(W + 117440512ull);        //  33,554,432  [bh,c][d][m]
    float* ds  = (float*)(W + 150994944ull);       //   1,048,576
    unsigned* mx = (unsigned*)(W + 152043520ull);  //   256
    bf16* pfh  = (bf16*)(W + 152043776ull);        //   16,384 proj hi frags
    bf16* pfl  = (bf16*)(W + 152060160ull);        //   16,384 proj lo frags

    hipLaunchKernelGGL(proj_split, dim3(4), dim3(256), 0, stream, proj, pfh, pfl, mx);
    hipLaunchKernelGGL(pre3, dim3(6144), dim3(256), 0, stream,
                       q, k, v, pfh, pfl, mx, qp, vbT);
    hipLaunchKernelGGL(feat_k, dim3(2048), dim3(256), 0, stream,
                       k, pfh, pfl, mx, kp, kpT);
    hipLaunchKernelGGL(chunk_mfma, dim3(2048), dim3(256), 0, stream, kpT, vbT, S, ds);
    hipLaunchKernelGGL(prefix_SD, dim3(1024), dim3(256), 0, stream, (unsigned*)S, ds);
    hipLaunchKernelGGL(attn_mfma, dim3(2048), dim3(256), 0, stream,
                       qp, kp, vbT, S, ds, out);
}